// Round 4
// baseline (466.971 us; speedup 1.0000x reference)
//
#include <hip/hip_runtime.h>
#include <stdint.h>

// Guided_Conv R4 (= R3 resubmit + hardened barriers; R3 hit an infra failure).
// Persistent pipelined blocks, ALL staging via registers.
// grid=768 (3 blocks/CU, 9 waves/block = 27/32 waves/CU), block=576.
// Patch assignment: blocks 0..255 own 6 patches, 256..767 own 5
// -> every CU hosts one 6-patch + two 5-patch blocks = 16 patches/CU, balanced.
//
// Pipeline (no global_load_lds, no hand-counted vmcnt — everything the
// compiler can track):
//   iter it: partA consumes gn/dn (patch m regs, loaded last iter):
//            GAP partial + conv-pixel scatter (guidance), ds_write depth->LDS.
//            Then ISSUE plain global loads of patch m+1 into gn/dn; they stay
//            in flight across B1..P4 (4 barriers of compute); the compiler
//            inserts the vmcnt wait at next iter's partA consumption.
//   Barrier = ONE asm volatile containing "s_waitcnt lgkmcnt(0); s_barrier"
//   with a "memory" clobber: two-sided compiler fence (no ds op may cross in
//   either direction — a bare s_barrier intrinsic is NOT a memory fence and
//   post-barrier ds_reads could otherwise be hoisted above it), while vmcnt
//   (the prefetch) intentionally stays in flight.
// Single depth LDS buffer: registers carry patch m+1 while LDS holds patch m.
// LDS ~33 KB/block.

#define LGKM0_BAR() \
    asm volatile("s_waitcnt lgkmcnt(0)\n\ts_barrier" ::: "memory")

__device__ __forceinline__ long patch_rowbase(int m) {
    const int b0 = m >> 8, pi = (m >> 4) & 15, pj = m & 15;
    return ((long)(b0 * 384 + pi * 24)) * 3456 + (long)pj * 216;
}

__global__ __launch_bounds__(576, 7) void fused_kernel(
    const float* __restrict__ g,
    const float* __restrict__ dep,
    const float* __restrict__ cw,
    const float* __restrict__ cb,
    const float* __restrict__ dw,
    const float* __restrict__ db,
    float* __restrict__ out)
{
    __shared__ __align__(16) float sdep[5184];   // depth patch [24][24][9] linear
    __shared__ __align__(16) float part2[576];   // GAP partials, [t]
    __shared__ __align__(16) float sw[216];      // w1[9][12] + w2t[9][12]
    __shared__ float cwT[729];                   // conv_w transposed [uv][o][ci]
    __shared__ float dwf[729];                   // dense_w [k][81]
    __shared__ float scratch[729];               // conv input pixels [9x9][ch]
    __shared__ float cbf[9];
    __shared__ float dbf[81];
    __shared__ float gapm[9];
    __shared__ float cful[81];                   // conv out [uv][o]

    const int bk = blockIdx.x;
    const int t  = threadIdx.x;
    int p0, np;
    if (bk < 256) { p0 = bk * 6;                np = 6; }
    else          { p0 = 1536 + (bk - 256) * 5; np = 5; }

    // ---- prologue: weights -> LDS (conv_w transposed for contiguous ci) ----
    for (int idx = t; idx < 729; idx += 576) {
        const int uv = idx / 81, rem = idx - uv * 81, o = rem / 9, ci = rem - o * 9;
        cwT[idx] = cw[uv * 81 + ci * 9 + o];
        dwf[idx] = dw[idx];
    }
    if (t < 9) cbf[t] = cb[t];
    if (t >= 64 && t < 145) dbf[t - 64] = db[t - 64];
    __syncthreads();   // full drain once (nothing else in flight yet)

    // ---- prime: load patch p0 into registers (perfectly coalesced, stride 576) ----
    float gn[9], dn[9];
    {
        const long rb = patch_rowbase(p0);
        #pragma unroll
        for (int k = 0; k < 9; ++k) {
            const int idx = t + 576 * k;
            const int r = idx / 216;                  // patch row
            const long a = rb + idx + (long)r * 3240; // rb + r*3456 + (idx - r*216)
            gn[k] = g[a];
            dn[k] = dep[a];
        }
    }

    for (int it = 0; it < np; ++it) {
        const int m = p0 + it;

        // ---- partA: consume gn/dn (patch m) ----
        {
            float s = 0.f;
            #pragma unroll
            for (int k = 0; k < 9; ++k) s += gn[k];
            part2[t] = s;                             // lane-contiguous, conflict-free
            #pragma unroll
            for (int k = 0; k < 9; ++k) sdep[t + 576 * k] = dn[k];
            const int ch = t % 9;
            #pragma unroll
            for (int k = 0; k < 9; ++k) {
                const int idx = t + 576 * k;
                const int r = idx / 216, x = idx - r * 216;
                const int c = x / 9;
                if (((r & 7) < 3) && ((c & 7) < 3)) { // rows/cols {0,1,2,8,9,10,16,17,18}
                    const int ri  = (r >> 3) * 3 + (r & 7);
                    const int ci2 = (c >> 3) * 3 + (c & 7);
                    scratch[(ri * 9 + ci2) * 9 + ch] = gn[k];
                }
            }
        }

        // ---- issue prefetch of patch m+1 (block-uniform branch); flies across B1..P4 ----
        if (it + 1 < np) {
            const long rb = patch_rowbase(m + 1);
            #pragma unroll
            for (int k = 0; k < 9; ++k) {
                const int idx = t + 576 * k;
                const int r = idx / 216;
                const long a = rb + idx + (long)r * 3240;
                gn[k] = g[a];
                dn[k] = dep[a];
            }
        }
        LGKM0_BAR();   // B1: part2/scratch/sdep visible

        // ---- B2 phase: strided 3x3 conv (t<81, waves 0-1) || GAP finish (wave 2) ----
        if (t < 81) {
            const int o = t % 9, uv = t / 9, v = uv % 3, u = uv / 3;
            float acc = cbf[o];
            #pragma unroll
            for (int du = 0; du < 3; ++du)
            #pragma unroll
            for (int dv = 0; dv < 3; ++dv) {
                const float* sp = &scratch[((u * 3 + du) * 9 + (v * 3 + dv)) * 9];
                const float* wp = &cwT[(du * 3 + dv) * 81 + o * 9];
                #pragma unroll
                for (int ci = 0; ci < 9; ++ci) acc += sp[ci] * wp[ci];
            }
            cful[t] = acc;
        } else if (t >= 128 && t < 137) {
            const int c = t - 128;
            float s = 0.f;
            #pragma unroll
            for (int j = 0; j < 64; ++j) s += part2[j * 9 + c];  // stride 9: no conflicts
            gapm[c] = s * (1.0f / 576.0f);
        }
        LGKM0_BAR();   // B2: cful/gapm visible

        // ---- B3 phase: dense + W2 clip (t<9, wave 0) || W1 clip (wave 1) ----
        if (t < 9) {
            float gv[9];
            #pragma unroll
            for (int k = 0; k < 9; ++k) gv[k] = gapm[k];
            float dvals[9]; float ss = 0.f;
            #pragma unroll
            for (int i = 0; i < 9; ++i) {
                float a = dbf[i * 9 + t];
                #pragma unroll
                for (int k = 0; k < 9; ++k) a += gv[k] * dwf[k * 81 + i * 9 + t];
                dvals[i] = a; ss += a * a;
            }
            const float sc2 = (ss > 1.0f) ? (1.0f / sqrtf(ss)) : 1.0f;
            #pragma unroll
            for (int i = 0; i < 9; ++i) sw[108 + t * 12 + i] = dvals[i] * sc2;
        } else if (t >= 64 && t < 73) {
            const int f = t - 64;
            float ss = 0.f;
            #pragma unroll
            for (int k = 0; k < 9; ++k) { const float cc = cful[k * 9 + f]; ss += cc * cc; }
            const float sc1 = (ss > 1.0f) ? (1.0f / sqrtf(ss)) : 1.0f;
            #pragma unroll
            for (int k = 0; k < 9; ++k) sw[k * 12 + f] = cful[k * 9 + f] * sc1;
        }
        LGKM0_BAR();   // B3: sw visible

        // ---- P4: 1 pixel/thread; taps scalar (stride-9, conflict-free);
        //      weights b128 (48B-aligned rows, broadcast) ----
        {
            const int row = t / 24, col = t - row * 24;
            float dc[9];
            #pragma unroll
            for (int i = 0; i < 9; ++i) dc[i] = 0.f;

            #pragma unroll
            for (int du = 0; du < 3; ++du) {
                const int r = row + du - 1;
                if (r < 0 || r > 23) continue;
                #pragma unroll
                for (int dv = 0; dv < 3; ++dv) {
                    const int c = col + dv - 1;
                    if (c < 0 || c > 23) continue;
                    const float* sp = &sdep[(r * 24 + c) * 9];
                    const float* wb = &sw[(du * 3 + dv) * 12];
                    const float4 W0 = *reinterpret_cast<const float4*>(wb);
                    const float4 W1 = *reinterpret_cast<const float4*>(wb + 4);
                    const float w8 = wb[8];
                    dc[0] += sp[0] * W0.x; dc[1] += sp[1] * W0.y; dc[2] += sp[2] * W0.z;
                    dc[3] += sp[3] * W0.w; dc[4] += sp[4] * W1.x; dc[5] += sp[5] * W1.y;
                    dc[6] += sp[6] * W1.z; dc[7] += sp[7] * W1.w; dc[8] += sp[8] * w8;
                }
            }

            float* op = out + (long)m * 5184 + t * 9;
            #pragma unroll
            for (int o = 0; o < 9; ++o) {
                const float* wb = &sw[108 + o * 12];
                const float4 W0 = *reinterpret_cast<const float4*>(wb);
                const float4 W1 = *reinterpret_cast<const float4*>(wb + 4);
                op[o] = dc[0] * W0.x + dc[1] * W0.y + dc[2] * W0.z + dc[3] * W0.w
                      + dc[4] * W1.x + dc[5] * W1.y + dc[6] * W1.z + dc[7] * W1.w
                      + dc[8] * wb[8];
            }
        }
        LGKM0_BAR();   // end-of-iter: P4 reads done before next partA overwrites LDS
    }
}

extern "C" void kernel_launch(void* const* d_in, const int* in_sizes, int n_in,
                              void* d_out, int out_size, void* d_ws, size_t ws_size,
                              hipStream_t stream) {
    const float* g  = (const float*)d_in[0];
    const float* dp = (const float*)d_in[1];
    const float* cw = (const float*)d_in[2];
    const float* cb = (const float*)d_in[3];
    const float* dw = (const float*)d_in[4];
    const float* db = (const float*)d_in[5];
    float* out = (float*)d_out;
    (void)d_ws; (void)ws_size;

    fused_kernel<<<dim3(768), dim3(576), 0, stream>>>(g, dp, cw, cb, dw, db, out);
}

// Round 5
// 271.944 us; speedup vs baseline: 1.7172x; 1.7172x over previous
//
#include <hip/hip_runtime.h>
#include <stdint.h>

// Guided_Conv R5 = R1-fused (verified 99.5 us/dispatch, clean traffic) with ONE
// delta: nontemporal output stores.
// Post-mortem R4: persistent 768-block pipeline inflated HBM traffic 3.5x
// (FETCH 382 MB, WRITE 231 MB) at the same ~1.9 TB/s achieved BW -> 331 us.
// Reverted. Achieved BW pins at ~1.9 TB/s across all measured variants, so
// time ~ hbm_bytes. R1's FETCH (92 MB) is already below unique input (166 MB)
// thanks to L3 residency across bench replays; footprint 249 MB ~= L3 256 MB,
// so the streaming output's write-allocate evicts input. nt stores keep the
// output out of L3 -> inputs become fully L3-resident -> FETCH should collapse.

__device__ __forceinline__ void gload16(const float* gsrc, float* ldst) {
    __builtin_amdgcn_global_load_lds(
        (__attribute__((address_space(1))) void*)gsrc,
        (__attribute__((address_space(3))) void*)ldst, 16, 0, 0);
}

__global__ __launch_bounds__(576, 6) void fused_kernel(
    const float* __restrict__ g,
    const float* __restrict__ dep,
    const float* __restrict__ cw,
    const float* __restrict__ cb,
    const float* __restrict__ dw,
    const float* __restrict__ db,
    float* __restrict__ out)
{
    __shared__ __align__(16) float sg[5184];   // guidance patch [24][24][9]
    __shared__ __align__(16) float sd[5184];   // depth patch    [24][24][9]
    __shared__ __align__(16) float cwf[729];   // conv_w [du][dv][ci][o]
    __shared__ __align__(16) float dwf[729];   // dense_w [k][81]
    __shared__ float cbf[9];
    __shared__ float dbf[81];
    __shared__ float cols[216];                // per-(col,f) sums over rows
    __shared__ float gapm[9];
    __shared__ float cful[81];                 // conv out [uv][o]
    __shared__ __align__(16) float sw[216];    // w1[9][12] + w2t[9][12] (pads unread)

    const int m = blockIdx.x;
    const int t = threadIdx.x;
    const int b0 = m >> 8, pi = (m >> 4) & 15, pj = m & 15;
    const long rowbase = ((long)(b0 * 384 + pi * 24)) * 3456 + (long)pj * 216;

    // ---- Phase 0: async-stage both patches (1296 float4 each) + weights ----
    for (int task = t; task < 1296; task += 576) {
        int r = task / 54, c4 = task - r * 54;
        gload16(g + rowbase + (long)r * 3456 + c4 * 4, sg + task * 4);
    }
    for (int task = t; task < 1296; task += 576) {
        int r = task / 54, c4 = task - r * 54;
        gload16(dep + rowbase + (long)r * 3456 + c4 * 4, sd + task * 4);
    }
    for (int idx = t; idx < 729; idx += 576) { cwf[idx] = cw[idx]; dwf[idx] = dw[idx]; }
    if (t < 9) cbf[t] = cb[t];
    if (t >= 64 && t < 145) dbf[t - 64] = db[t - 64];
    __syncthreads();   // drains vmcnt(0) -> sg/sd resident

    // ---- P1: column sums (t<216)  ||  strided 3x3 conv (81 thr, waves 4-5) ----
    if (t < 216) {
        float s = 0.f;
        #pragma unroll
        for (int r = 0; r < 24; ++r) s += sg[r * 216 + t];
        cols[t] = s;
    } else if (t >= 256 && t < 337) {
        const int q = t - 256;
        const int o = q % 9, uv = q / 9, v = uv % 3, u = uv / 3;
        float acc = cbf[o];
        #pragma unroll
        for (int du = 0; du < 3; ++du)
        #pragma unroll
        for (int dv = 0; dv < 3; ++dv) {
            const float* gp2 = &sg[(u * 8 + du) * 216 + (v * 8 + dv) * 9];
            const float* wp  = &cwf[(du * 3 + dv) * 81 + o];
            #pragma unroll
            for (int ci = 0; ci < 9; ++ci) acc += gp2[ci] * wp[ci * 9];
        }
        cful[q] = acc;
    }
    __syncthreads();

    // ---- P2: GAP (t<9)  ||  W1 clip+store (9 thr, wave 1) ----
    if (t < 9) {
        float s = 0.f;
        #pragma unroll
        for (int c = 0; c < 24; ++c) s += cols[c * 9 + t];
        gapm[t] = s * (1.0f / 576.0f);
    } else if (t >= 64 && t < 73) {
        const int f = t - 64;
        float s = 0.f;
        #pragma unroll
        for (int k = 0; k < 9; ++k) { float c = cful[k * 9 + f]; s += c * c; }
        const float scale = (s > 1.0f) ? (1.0f / sqrtf(s)) : 1.0f;
        #pragma unroll
        for (int k = 0; k < 9; ++k) sw[k * 12 + f] = cful[k * 9 + f] * scale;
    }
    __syncthreads();

    // ---- P3: dense + W2 clip fused (thread t = output o; sums over i) ----
    if (t < 9) {
        float gv[9];
        #pragma unroll
        for (int k = 0; k < 9; ++k) gv[k] = gapm[k];
        float d[9];
        float s = 0.f;
        #pragma unroll
        for (int i = 0; i < 9; ++i) {
            float a = dbf[i * 9 + t];
            #pragma unroll
            for (int k = 0; k < 9; ++k) a += gv[k] * dwf[k * 81 + i * 9 + t];
            d[i] = a; s += a * a;
        }
        const float scale = (s > 1.0f) ? (1.0f / sqrtf(s)) : 1.0f;
        #pragma unroll
        for (int i = 0; i < 9; ++i) sw[108 + t * 12 + i] = d[i] * scale;
    }
    __syncthreads();

    // ---- P4: apply — 1 pixel/thread, predicated taps, conflict-free reads;
    //      NONTEMPORAL stores (keep output out of L2/L3 so inputs stay resident) ----
    {
        const int row = t / 24;
        const int col = t - row * 24;
        float dc[9];
        #pragma unroll
        for (int i = 0; i < 9; ++i) dc[i] = 0.f;

        #pragma unroll
        for (int du = 0; du < 3; ++du) {
            const int r = row + du - 1;
            if (r < 0 || r > 23) continue;
            #pragma unroll
            for (int dv = 0; dv < 3; ++dv) {
                const int c = col + dv - 1;
                if (c < 0 || c > 23) continue;
                const float* sp = &sd[r * 216 + c * 9];    // lane stride 9: conflict-free
                const float* wv = &sw[(du * 3 + dv) * 12]; // broadcast, 16B-aligned
                #pragma unroll
                for (int i = 0; i < 9; ++i) dc[i] += sp[i] * wv[i];
            }
        }

        float* op = out + (long)m * 5184 + t * 9;
        #pragma unroll
        for (int o = 0; o < 9; ++o) {
            const float* wv = &sw[108 + o * 12];
            float a = 0.f;
            #pragma unroll
            for (int i = 0; i < 9; ++i) a += dc[i] * wv[i];
            __builtin_nontemporal_store(a, op + o);
        }
    }
}

extern "C" void kernel_launch(void* const* d_in, const int* in_sizes, int n_in,
                              void* d_out, int out_size, void* d_ws, size_t ws_size,
                              hipStream_t stream) {
    const float* g  = (const float*)d_in[0];
    const float* dp = (const float*)d_in[1];
    const float* cw = (const float*)d_in[2];
    const float* cb = (const float*)d_in[3];
    const float* dw = (const float*)d_in[4];
    const float* db = (const float*)d_in[5];
    float* out = (float*)d_out;
    (void)d_ws; (void)ws_size;

    fused_kernel<<<dim3(4096), dim3(576), 0, stream>>>(g, dp, cw, cb, dw, db, out);
}

// Round 6
// 227.924 us; speedup vs baseline: 2.0488x; 1.1931x over previous
//
#include <hip/hip_runtime.h>
#include <stdint.h>

// Guided_Conv R6 = R1-fused base + depth-fetch/compute overlap (T14 + counted vmcnt).
// Post-mortems:
//   R4: persistent 768-block pipeline -> 3.5x HBM traffic, 331 us. Dead.
//   R5: nt scalar stores -> partial-line write amplification (WRITE 83->217 MB,
//       145 us) while FETCH stayed EXACTLY 92 MB -> input eviction comes from
//       the harness's output re-poison between iterations, not our stores.
//       => traffic floor is fixed at ~175 MB; the only lever left is achieved BW.
// R1's burst-then-drain (__syncthreads = vmcnt(0)) gives ~30% HBM duty -> 1.9 TB/s.
// R6: guidance still DMA->LDS (needed cross-thread at P1); depth via registers,
// issued in phase 0, consumed (ds_write->sd) only in the P3 phase -> the 9 dep
// loads/thread stay in flight across P1..P3 behind lgkm-only barriers.
// First barrier is counted: every wave issues its guidance DMAs THEN exactly 9
// dep loads (5184/576 uniform), so s_waitcnt vmcnt(9) retires all DMAs (and all
// earlier weight loads were already retired by their pre-barrier ds_write waits,
// in-order). sched_barrier(0) pins issue order against compiler reordering.

#define SBAR() __builtin_amdgcn_sched_barrier(0)
#define LGKM0_BAR() \
    asm volatile("s_waitcnt lgkmcnt(0)\n\ts_barrier" ::: "memory")
#define VMCNT9_BAR() \
    asm volatile("s_waitcnt vmcnt(9) lgkmcnt(0)\n\ts_barrier" ::: "memory")

__device__ __forceinline__ void gload16(const float* gsrc, float* ldst) {
    __builtin_amdgcn_global_load_lds(
        (__attribute__((address_space(1))) void*)gsrc,
        (__attribute__((address_space(3))) void*)ldst, 16, 0, 0);
}

__global__ __launch_bounds__(576, 6) void fused_kernel(
    const float* __restrict__ g,
    const float* __restrict__ dep,
    const float* __restrict__ cw,
    const float* __restrict__ cb,
    const float* __restrict__ dw,
    const float* __restrict__ db,
    float* __restrict__ out)
{
    __shared__ __align__(16) float sg[5184];   // guidance patch [24][24][9]
    __shared__ __align__(16) float sd[5184];   // depth patch    [24][24][9]
    __shared__ __align__(16) float cwf[729];   // conv_w [du][dv][ci][o]
    __shared__ __align__(16) float dwf[729];   // dense_w [k][81]
    __shared__ float cbf[9];
    __shared__ float dbf[81];
    __shared__ float cols[216];                // per-(col,f) sums over rows
    __shared__ float gapm[9];
    __shared__ float cful[81];                 // conv out [uv][o]
    __shared__ __align__(16) float sw[216];    // w1[9][12] + w2t[9][12] (pads unread)

    const int m = blockIdx.x;
    const int t = threadIdx.x;
    const int b0 = m >> 8, pi = (m >> 4) & 15, pj = m & 15;
    const long rowbase = ((long)(b0 * 384 + pi * 24)) * 3456 + (long)pj * 216;

    // ---- Phase 0a: weights (plain load + ds_write; compiler retires the loads
    //      before each consuming ds_write -> 0 outstanding vmem at SBAR) ----
    for (int idx = t; idx < 729; idx += 576) { cwf[idx] = cw[idx]; dwf[idx] = dw[idx]; }
    if (t < 9) cbf[t] = cb[t];
    if (t >= 64 && t < 145) dbf[t - 64] = db[t - 64];
    SBAR();

    // ---- Phase 0b: guidance DMA -> sg (2-3 gload16 per wave) ----
    for (int task = t; task < 1296; task += 576) {
        int r = task / 54, c4 = task - r * 54;
        gload16(g + rowbase + (long)r * 3456 + c4 * 4, sg + task * 4);
    }
    SBAR();

    // ---- Phase 0c: depth -> registers (exactly 9 loads/thread, coalesced) ----
    float dn[9];
    #pragma unroll
    for (int k = 0; k < 9; ++k) {
        const int idx = t + 576 * k;
        const int r = idx / 216;                    // patch row
        dn[k] = dep[rowbase + idx + (long)r * 3240]; // rb + r*3456 + (idx - r*216)
    }
    SBAR();

    // guidance DMA + weight LDS writes complete; 9 dep loads stay in flight
    VMCNT9_BAR();

    // ---- P1: column sums (t<216)  ||  strided 3x3 conv (81 thr, waves 4-5) ----
    if (t < 216) {
        float s = 0.f;
        #pragma unroll
        for (int r = 0; r < 24; ++r) s += sg[r * 216 + t];
        cols[t] = s;
    } else if (t >= 256 && t < 337) {
        const int q = t - 256;
        const int o = q % 9, uv = q / 9, v = uv % 3, u = uv / 3;
        float acc = cbf[o];
        #pragma unroll
        for (int du = 0; du < 3; ++du)
        #pragma unroll
        for (int dv = 0; dv < 3; ++dv) {
            const float* gp2 = &sg[(u * 8 + du) * 216 + (v * 8 + dv) * 9];
            const float* wp  = &cwf[(du * 3 + dv) * 81 + o];
            #pragma unroll
            for (int ci = 0; ci < 9; ++ci) acc += gp2[ci] * wp[ci * 9];
        }
        cful[q] = acc;
    }
    LGKM0_BAR();   // dep loads remain in flight (no vmcnt here)

    // ---- P2: GAP (t<9)  ||  W1 clip+store (9 thr, wave 1) ----
    if (t < 9) {
        float s = 0.f;
        #pragma unroll
        for (int c = 0; c < 24; ++c) s += cols[c * 9 + t];
        gapm[t] = s * (1.0f / 576.0f);
    } else if (t >= 64 && t < 73) {
        const int f = t - 64;
        float s = 0.f;
        #pragma unroll
        for (int k = 0; k < 9; ++k) { float c = cful[k * 9 + f]; s += c * c; }
        const float scale = (s > 1.0f) ? (1.0f / sqrtf(s)) : 1.0f;
        #pragma unroll
        for (int k = 0; k < 9; ++k) sw[k * 12 + f] = cful[k * 9 + f] * scale;
    }
    LGKM0_BAR();

    // ---- P3: dep regs -> sd (all threads; compiler inserts the vmcnt wait
    //      here = consumption point) || dense + W2 clip (t<9) ----
    #pragma unroll
    for (int k = 0; k < 9; ++k) sd[t + 576 * k] = dn[k];   // lane-contiguous, conflict-free
    if (t < 9) {
        float gv[9];
        #pragma unroll
        for (int k = 0; k < 9; ++k) gv[k] = gapm[k];
        float d[9];
        float s = 0.f;
        #pragma unroll
        for (int i = 0; i < 9; ++i) {
            float a = dbf[i * 9 + t];
            #pragma unroll
            for (int k = 0; k < 9; ++k) a += gv[k] * dwf[k * 81 + i * 9 + t];
            d[i] = a; s += a * a;
        }
        const float scale = (s > 1.0f) ? (1.0f / sqrtf(s)) : 1.0f;
        #pragma unroll
        for (int i = 0; i < 9; ++i) sw[108 + t * 12 + i] = d[i] * scale;
    }
    LGKM0_BAR();   // sd + sw visible

    // ---- P4: apply — 1 pixel/thread, predicated taps, conflict-free reads;
    //      plain scalar stores (L2 coalesces to full lines — R5 proved nt hurts) ----
    {
        const int row = t / 24;
        const int col = t - row * 24;
        float dc[9];
        #pragma unroll
        for (int i = 0; i < 9; ++i) dc[i] = 0.f;

        #pragma unroll
        for (int du = 0; du < 3; ++du) {
            const int r = row + du - 1;
            if (r < 0 || r > 23) continue;
            #pragma unroll
            for (int dv = 0; dv < 3; ++dv) {
                const int c = col + dv - 1;
                if (c < 0 || c > 23) continue;
                const float* sp = &sd[r * 216 + c * 9];    // lane stride 9: conflict-free
                const float* wv = &sw[(du * 3 + dv) * 12]; // broadcast, 16B-aligned
                #pragma unroll
                for (int i = 0; i < 9; ++i) dc[i] += sp[i] * wv[i];
            }
        }

        float* op = out + (long)m * 5184 + t * 9;
        #pragma unroll
        for (int o = 0; o < 9; ++o) {
            const float* wv = &sw[108 + o * 12];
            float a = 0.f;
            #pragma unroll
            for (int i = 0; i < 9; ++i) a += dc[i] * wv[i];
            op[o] = a;
        }
    }
}

extern "C" void kernel_launch(void* const* d_in, const int* in_sizes, int n_in,
                              void* d_out, int out_size, void* d_ws, size_t ws_size,
                              hipStream_t stream) {
    const float* g  = (const float*)d_in[0];
    const float* dp = (const float*)d_in[1];
    const float* cw = (const float*)d_in[2];
    const float* cb = (const float*)d_in[3];
    const float* dw = (const float*)d_in[4];
    const float* db = (const float*)d_in[5];
    float* out = (float*)d_out;
    (void)d_ws; (void)ws_size;

    fused_kernel<<<dim3(4096), dim3(576), 0, stream>>>(g, dp, cw, cb, dw, db, out);
}

// Round 7
// 225.974 us; speedup vs baseline: 2.0665x; 1.0086x over previous
//
#include <hip/hip_runtime.h>
#include <stdint.h>

// Guided_Conv R7 = R6 + LDS-pipe diet. R6 counters: FETCH 92/WRITE 83 MB fixed,
// all visible pipes <40% busy -> the governing resource is the (uncounted) LDS
// pipe: ~170 DS instrs/thread ~= 60-80 us/CU at measured b32=5.8/b128=12 cyc.
// Two deltas, both arithmetic-identical:
//  1) weight reads via v_readlane: w1p/w2p (81+81 floats) live in 4 VGPRs/wave
//     (lane l holds w[l]); each weight = readlane(imm) -> SGPR -> FMA s-operand.
//     -54 LDS instrs/thread, +~324 VALU cyc on the 27%-busy VALU pipe.
//  2) depth LDS padded [576][12] (48B/pixel, 16B-aligned) -> taps are
//     2x ds_read_b128 + 1x b32 (27 instrs vs 81). Stride-12 = 4-way bank
//     grouping but data-path-balanced; SQ_LDS_BANK_CONFLICT will arbitrate.
//     +7KB paid by overlaying sd onto sg (sg dead after P1; sd written in P3,
//     two barriers later). LDS 50 -> ~36 KB (occupancy still wave-capped at 3).

#define SBAR() __builtin_amdgcn_sched_barrier(0)
#define LGKM0_BAR() \
    asm volatile("s_waitcnt lgkmcnt(0)\n\ts_barrier" ::: "memory")
#define VMCNT9_BAR() \
    asm volatile("s_waitcnt vmcnt(9) lgkmcnt(0)\n\ts_barrier" ::: "memory")

__device__ __forceinline__ void gload16(const float* gsrc, float* ldst) {
    __builtin_amdgcn_global_load_lds(
        (__attribute__((address_space(1))) void*)gsrc,
        (__attribute__((address_space(3))) void*)ldst, 16, 0, 0);
}

__device__ __forceinline__ float rlane(float v, int l) {
    return __int_as_float(__builtin_amdgcn_readlane(__float_as_int(v), l));
}

__global__ __launch_bounds__(576, 6) void fused_kernel(
    const float* __restrict__ g,
    const float* __restrict__ dep,
    const float* __restrict__ cw,
    const float* __restrict__ cb,
    const float* __restrict__ dw,
    const float* __restrict__ db,
    float* __restrict__ out)
{
    // overlay: phase 0-1 = guidance [24][24][9] (5184 floats);
    //          phase 3-4 = depth   [576][12]   (6912 floats, 16B-aligned rows)
    __shared__ __align__(16) float s_gd[6912];
    __shared__ __align__(16) float cwf[729];   // conv_w [du][dv][ci][o]
    __shared__ __align__(16) float dwf[729];   // dense_w [k][81]
    __shared__ float cbf[9];
    __shared__ float dbf[81];
    __shared__ float cols[216];                // per-(col,f) sums over rows
    __shared__ float gapm[9];
    __shared__ float cful[81];                 // conv out [uv][o]
    __shared__ __align__(16) float sw[256];    // w1p[81] @0, w2p[81] @96

    const int m = blockIdx.x;
    const int t = threadIdx.x;
    const int b0 = m >> 8, pi = (m >> 4) & 15, pj = m & 15;
    const long rowbase = ((long)(b0 * 384 + pi * 24)) * 3456 + (long)pj * 216;

    // ---- Phase 0a: weights (plain load + ds_write, retired pre-barrier) ----
    for (int idx = t; idx < 729; idx += 576) { cwf[idx] = cw[idx]; dwf[idx] = dw[idx]; }
    if (t < 9) cbf[t] = cb[t];
    if (t >= 64 && t < 145) dbf[t - 64] = db[t - 64];
    SBAR();

    // ---- Phase 0b: guidance DMA -> s_gd (sg view, linear [r][c][9]) ----
    for (int task = t; task < 1296; task += 576) {
        int r = task / 54, c4 = task - r * 54;
        gload16(g + rowbase + (long)r * 3456 + c4 * 4, s_gd + task * 4);
    }
    SBAR();

    // ---- Phase 0c: depth -> registers (exactly 9 coalesced loads/thread) ----
    float dn[9];
    #pragma unroll
    for (int k = 0; k < 9; ++k) {
        const int idx = t + 576 * k;
        const int r = idx / 216;
        dn[k] = dep[rowbase + idx + (long)r * 3240];
    }
    SBAR();

    VMCNT9_BAR();   // guidance DMA done; 9 dep loads stay in flight

    // ---- P1: column sums (t<216)  ||  strided 3x3 conv (81 thr, waves 4-5) ----
    if (t < 216) {
        float s = 0.f;
        #pragma unroll
        for (int r = 0; r < 24; ++r) s += s_gd[r * 216 + t];
        cols[t] = s;
    } else if (t >= 256 && t < 337) {
        const int q = t - 256;
        const int o = q % 9, uv = q / 9, v = uv % 3, u = uv / 3;
        float acc = cbf[o];
        #pragma unroll
        for (int du = 0; du < 3; ++du)
        #pragma unroll
        for (int dv = 0; dv < 3; ++dv) {
            const float* gp2 = &s_gd[(u * 8 + du) * 216 + (v * 8 + dv) * 9];
            const float* wp  = &cwf[(du * 3 + dv) * 81 + o];
            #pragma unroll
            for (int ci = 0; ci < 9; ++ci) acc += gp2[ci] * wp[ci * 9];
        }
        cful[q] = acc;
    }
    LGKM0_BAR();   // all sg reads complete block-wide (dep loads still in flight)

    // ---- P2: GAP (t<9)  ||  W1 clip -> packed w1p (9 thr, wave 1) ----
    if (t < 9) {
        float s = 0.f;
        #pragma unroll
        for (int c = 0; c < 24; ++c) s += cols[c * 9 + t];
        gapm[t] = s * (1.0f / 576.0f);
    } else if (t >= 64 && t < 73) {
        const int f = t - 64;
        float s = 0.f;
        #pragma unroll
        for (int k = 0; k < 9; ++k) { float c = cful[k * 9 + f]; s += c * c; }
        const float scale = (s > 1.0f) ? (1.0f / sqrtf(s)) : 1.0f;
        #pragma unroll
        for (int k = 0; k < 9; ++k) sw[k * 9 + f] = cful[k * 9 + f] * scale;
    }
    LGKM0_BAR();

    // ---- P3: dep regs -> sd view [pix][12] (vmcnt wait lands here)
    //      || dense + W2 clip -> packed w2p (t<9) ----
    #pragma unroll
    for (int k = 0; k < 9; ++k) {
        const int idx = t + 576 * k;
        const int pix = idx / 9, ch = idx - pix * 9;
        s_gd[pix * 12 + ch] = dn[k];
    }
    if (t < 9) {
        float gv[9];
        #pragma unroll
        for (int k = 0; k < 9; ++k) gv[k] = gapm[k];
        float d[9];
        float s = 0.f;
        #pragma unroll
        for (int i = 0; i < 9; ++i) {
            float a = dbf[i * 9 + t];
            #pragma unroll
            for (int k = 0; k < 9; ++k) a += gv[k] * dwf[k * 81 + i * 9 + t];
            d[i] = a; s += a * a;
        }
        const float scale = (s > 1.0f) ? (1.0f / sqrtf(s)) : 1.0f;
        #pragma unroll
        for (int i = 0; i < 9; ++i) sw[96 + t * 9 + i] = d[i] * scale;
    }
    LGKM0_BAR();   // sd + packed weights visible

    // ---- P4: 1 pixel/thread. Weights: 4 VGPRs/wave + readlane (zero LDS).
    //      Taps: 2x b128 + 1x b32 from padded sd. ----
    {
        const int l = t & 63;
        const float a1 = sw[l];          // w1p[0..63]
        const float a2 = sw[64 + l];     // w1p[64..80] live in lanes 0..16
        const float b1 = sw[96 + l];     // w2p[0..63]
        const float b2 = sw[160 + l];    // w2p[64..80] live in lanes 0..16

        const int row = t / 24;
        const int col = t - row * 24;
        float dc[9];
        #pragma unroll
        for (int i = 0; i < 9; ++i) dc[i] = 0.f;

        #pragma unroll
        for (int du = 0; du < 3; ++du) {
            const int r = row + du - 1;
            if (r < 0 || r > 23) continue;
            #pragma unroll
            for (int dv = 0; dv < 3; ++dv) {
                const int c = col + dv - 1;
                if (c < 0 || c > 23) continue;
                const float* sp = &s_gd[(r * 24 + c) * 12];
                const float4 A = *reinterpret_cast<const float4*>(sp);
                const float4 B = *reinterpret_cast<const float4*>(sp + 4);
                const float a8 = sp[8];
                const int tap = du * 3 + dv;
                const float v[9] = { A.x, A.y, A.z, A.w, B.x, B.y, B.z, B.w, a8 };
                #pragma unroll
                for (int i = 0; i < 9; ++i) {
                    const int wi = tap * 9 + i;                       // compile-time
                    const float w = (wi < 64) ? rlane(a1, wi) : rlane(a2, wi - 64);
                    dc[i] += v[i] * w;
                }
            }
        }

        float* op = out + (long)m * 5184 + t * 9;
        #pragma unroll
        for (int o = 0; o < 9; ++o) {
            float a = 0.f;
            #pragma unroll
            for (int i = 0; i < 9; ++i) {
                const int wi = o * 9 + i;                             // compile-time
                const float w = (wi < 64) ? rlane(b1, wi) : rlane(b2, wi - 64);
                a += dc[i] * w;
            }
            op[o] = a;
        }
    }
}

extern "C" void kernel_launch(void* const* d_in, const int* in_sizes, int n_in,
                              void* d_out, int out_size, void* d_ws, size_t ws_size,
                              hipStream_t stream) {
    const float* g  = (const float*)d_in[0];
    const float* dp = (const float*)d_in[1];
    const float* cw = (const float*)d_in[2];
    const float* cb = (const float*)d_in[3];
    const float* dw = (const float*)d_in[4];
    const float* db = (const float*)d_in[5];
    float* out = (float*)d_out;
    (void)d_ws; (void)ws_size;

    fused_kernel<<<dim3(4096), dim3(576), 0, stream>>>(g, dp, cw, cb, dw, db, out);
}